// Round 5
// baseline (151.429 us; speedup 1.0000x reference)
//
#include <hip/hip_runtime.h>
#include <hip/hip_bf16.h>

typedef unsigned short u16;
typedef __attribute__((ext_vector_type(8))) short short8;
typedef __attribute__((ext_vector_type(4))) float f32x4;
typedef __attribute__((ext_vector_type(16))) float f32x16;
typedef __attribute__((ext_vector_type(4))) unsigned short u16x4;

#define DEVINL __device__ __forceinline__

DEVINL u16 f2bf(float f) {
    union { float f; unsigned u; } x; x.f = f;
    unsigned u = x.u;
    u += 0x7fffu + ((u >> 16) & 1u);   // round-to-nearest-even
    return (u16)(u >> 16);
}

DEVINL void gload_lds16(const void* g, void* l) {
    __builtin_amdgcn_global_load_lds(
        (const __attribute__((address_space(1))) unsigned*)g,
        (__attribute__((address_space(3))) unsigned*)l, 16, 0, 0);
}

// XOR swizzle for 128B-stride LDS rows: spreads 16B slots across banks.
DEVINL int swz(int row) { return (((row & 7) ^ ((row >> 3) & 7)) << 4); }

// v_permlane32_swap: after call, for lane<32: a=own a, b=partner's a;
// for lane>=32: a=partner's b, b=own b.
DEVINL void swap32(unsigned& a, unsigned& b) {
#if __has_builtin(__builtin_amdgcn_permlane32_swap)
    typedef __attribute__((ext_vector_type(2))) unsigned uv2;
    uv2 r = __builtin_amdgcn_permlane32_swap(a, b, false, false);
    a = r.x; b = r.y;
#else
    int h = ((int)(threadIdx.x & 63)) >> 5;
    unsigned pa = (unsigned)__shfl_xor((int)a, 32);
    unsigned pb = (unsigned)__shfl_xor((int)b, 32);
    unsigned na = h ? pb : a;
    unsigned nb = h ? b : pa;
    a = na; b = nb;
#endif
}

// ---------------- convert x (fp32 -> bf16), vectorized ----------------
__global__ void k_conv_x(const float* __restrict__ in, u16* __restrict__ out, int n4) {
    int i = blockIdx.x * blockDim.x + threadIdx.x;
    int stride = gridDim.x * blockDim.x;
    for (; i < n4; i += stride) {
        float4 v = ((const float4*)in)[i];
        u16x4 o;
        o.x = f2bf(v.x); o.y = f2bf(v.y); o.z = f2bf(v.z); o.w = f2bf(v.w);
        ((u16x4*)out)[i] = o;
    }
}

// ---------------- transpose + convert: in [R][C] fp32 -> out [C][R] bf16 ----------------
__global__ void k_transpose_bf(const float* __restrict__ in, u16* __restrict__ out, int R, int C) {
    __shared__ float t[32][33];
    int c0 = blockIdx.x * 32, r0 = blockIdx.y * 32;
    int tx = threadIdx.x, ty = threadIdx.y;
    #pragma unroll
    for (int j = 0; j < 32; j += 8)
        t[ty + j][tx] = in[(size_t)(r0 + ty + j) * C + c0 + tx];
    __syncthreads();
    #pragma unroll
    for (int j = 0; j < 32; j += 8)
        out[(size_t)(c0 + ty + j) * R + r0 + tx] = f2bf(t[tx][ty + j]);
}

// ---------------- GEMM v2: 3-stage counted-vmcnt pipeline ----------------
// C[M][N] = A[M][K] @ BT[N][K]^T, bf16 in, bf16/f32 out.
// BMxBN tile, BK=32, 512 threads = 8 waves (2M x 4N), triple-buffered LDS,
// ONE raw s_barrier per K-step, vmcnt(L) counted waits (never 0 until last iter).
template<int BM, int BN, bool OUT_BF16>
__global__ __launch_bounds__(512, 2)
void k_gemm_p(const u16* __restrict__ A, const u16* __restrict__ BT,
              void* __restrict__ C, int N, int K) {
    constexpr int BK = 32;
    constexpr int AI = BM / 128;               // gload issues per A tile (8KB each)
    constexpr int BI = BN / 128;
    constexpr int LOADS = AI + BI;             // gloads per K-tile per thread
    constexpr int MF = BM / 2 / 16;            // per-wave M frags (WM=2)
    constexpr int NF = BN / 4 / 16;            // per-wave N frags (WN=4)
    constexpr int ABYTES = BM * BK * 2;
    constexpr int BBYTES = BN * BK * 2;
    constexpr int TBYTES = ABYTES + BBYTES;
    __shared__ char lds[3 * TBYTES];

    const int tid  = threadIdx.x;
    const int lane = tid & 63;
    const int lo   = lane & 15;
    const int hi   = lane >> 4;
    const int wave = tid >> 6;
    const int wm   = wave >> 2;
    const int wn   = wave & 3;

    // XCD-aware bijective block swizzle (nwg % 8 == 0 for our grids)
    const int gx   = gridDim.x;
    const int nwg  = gx * gridDim.y;
    const int orig = blockIdx.y * gx + blockIdx.x;
    const int wg   = (orig & 7) * (nwg >> 3) + (orig >> 3);
    const long row0 = (long)(wg / gx) * BM;
    const long col0 = (long)(wg % gx) * BN;

    f32x4 acc[MF][NF] = {};

    const int r0s = tid >> 2;                  // staging row within 128-row chunk
    const int sl  = tid & 3;                   // staging 16B slot

    const int NT = K >> 5;

    // stage tile t into buffer t%3 (source-side XOR swizzle, linear LDS dest)
    auto stage = [&](int t) {
        char* base = lds + (t % 3) * TBYTES;
        const int kb = t * BK;
        #pragma unroll
        for (int i = 0; i < AI; i++) {
            int r  = i * 128 + r0s;
            int kc = sl ^ (r & 3);
            gload_lds16(A + (row0 + r) * (size_t)K + kb + kc * 8,
                        base + i * 8192 + tid * 16);
        }
        #pragma unroll
        for (int i = 0; i < BI; i++) {
            int r  = i * 128 + r0s;
            int kc = sl ^ (r & 3);
            gload_lds16(BT + (col0 + r) * (size_t)K + kb + kc * 8,
                        base + ABYTES + i * 8192 + tid * 16);
        }
    };

    stage(0);
    stage(1);

    for (int t = 0; t < NT; t++) {
        // counted wait: own tile-t loads done; tile-t+1's stay in flight
        if (t + 1 < NT) {
            if constexpr (LOADS == 4) asm volatile("s_waitcnt vmcnt(4)" ::: "memory");
            else                      asm volatile("s_waitcnt vmcnt(3)" ::: "memory");
        } else {
            asm volatile("s_waitcnt vmcnt(0)" ::: "memory");
        }
        __builtin_amdgcn_s_barrier();          // all waves confirmed tile t resident,
        __builtin_amdgcn_sched_barrier(0);     // and done reading buffer (t+2)%3

        if (t + 2 < NT) stage(t + 2);

        const char* ab = lds + (t % 3) * TBYTES;
        const char* bb = ab + ABYTES;

        short8 af[MF], bfr[NF];
        #pragma unroll
        for (int m = 0; m < MF; m++) {
            int r = wm * (BM / 2) + m * 16 + lo;
            af[m] = *(const short8*)(ab + r * 64 + ((hi * 16) ^ ((r & 3) << 4)));
        }
        #pragma unroll
        for (int n = 0; n < NF; n++) {
            int r = wn * (BN / 4) + n * 16 + lo;
            bfr[n] = *(const short8*)(bb + r * 64 + ((hi * 16) ^ ((r & 3) << 4)));
        }

        __builtin_amdgcn_s_setprio(1);
        #pragma unroll
        for (int m = 0; m < MF; m++)
            #pragma unroll
            for (int n = 0; n < NF; n++)
                acc[m][n] = __builtin_amdgcn_mfma_f32_16x16x32_bf16(af[m], bfr[n], acc[m][n], 0, 0, 0);
        __builtin_amdgcn_s_setprio(0);
    }

    const int rl = hi * 4;
    #pragma unroll
    for (int m = 0; m < MF; m++)
        #pragma unroll
        for (int n = 0; n < NF; n++)
            #pragma unroll
            for (int r = 0; r < 4; r++) {
                long row = row0 + wm * (BM / 2) + m * 16 + rl + r;
                long col = col0 + wn * (BN / 4) + n * 16 + lo;
                if constexpr (OUT_BF16)
                    ((u16*)C)[row * (size_t)N + col] = f2bf(acc[m][n][r]);
                else
                    ((float*)C)[row * (size_t)N + col] = acc[m][n][r];
            }
}

// ---------------- Flash attention v3: swapped-operand 32x32, in-register softmax --------
// grid: 1024 blocks (8 qi x 128 bh), longest-first. Block = 4 waves x 32 q-rows = 128 q.
// KVBLK = 64. Swapped QK^T: S^T = K·Q^T (lane owns q = lane&31). Swapped PV: O^T = V^T·P^T.
#define SCALE_L2E 0.18033688011112042f  // (1/sqrt(64)) * log2(e)

__global__ __launch_bounds__(256, 2)
void k_attn(const u16* __restrict__ qkv, u16* __restrict__ y) {
    constexpr int S = 1024, E = 1024, TE = 3072;
    __shared__ u16 Kt[64 * 64];   // [kv][d], swizzled rows (128B)
    __shared__ u16 Vt[64 * 64];   // [d][kv], swizzled rows (128B)

    const int tid  = threadIdx.x;
    const int lane = tid & 63;
    const int l31  = lane & 31;
    const int hA   = lane >> 5;
    const int wave = tid >> 6;

    const int qi = 7 - (int)(blockIdx.x >> 7);   // longest first
    const int bh = blockIdx.x & 127;
    const int b  = bh >> 4;
    const int h  = bh & 15;
    const int q0 = qi * 128;
    const size_t rowbase = (size_t)b * S;
    const int qg = q0 + wave * 32 + l31;         // this lane's q-row

    // Q fragments: lane holds Q[qg][kd*16 + hA*8 + 0..7] for kd=0..3
    short8 qf[4];
    {
        const u16* qp = qkv + (rowbase + qg) * TE + h * 64 + hA * 8;
        #pragma unroll
        for (int kd = 0; kd < 4; kd++) qf[kd] = *(const short8*)(qp + kd * 16);
    }

    f32x16 o0 = {}, o1 = {};          // O^T: lane col q=l31, rows d = (r&3)+8*(r>>2)+4*hA (+32 for o1)
    float ms = -1e30f, lsum = 0.f;    // running max (exp2-scaled) and denom, per q-row

    // staging indices
    const int kr0 = (wave << 3) + (lane >> 3);
    const int kcb = (lane & 7) * 16;
    const int vkv = (tid >> 3) * 2;
    const int vdc = (tid & 7) * 8;

    const int ntiles = 2 * qi + 2;
    for (int t = 0; t < ntiles; ++t) {
        const int kv0 = t * 64;
        __syncthreads();
        // ---- stage K via global_load_lds with pre-swizzled source ----
        #pragma unroll
        for (int it = 0; it < 2; it++) {
            int r = kr0 + it * 32;
            const char* src = (const char*)qkv
                + (((rowbase + kv0 + r) * TE + E + h * 64) << 1) + (kcb ^ swz(r));
            gload_lds16(src, (char*)Kt + wave * 1024 + it * 4096);
        }
        // ---- stage V^T: coalesced row loads, swizzled b32 pair writes ----
        {
            const u16* vsrc = qkv + (rowbase + kv0 + vkv) * TE + 2 * E + h * 64 + vdc;
            short8 v0 = *(const short8*)vsrc;
            short8 v1 = *(const short8*)(vsrc + TE);
            #pragma unroll
            for (int j = 0; j < 8; j++) {
                int d = vdc + j;
                unsigned val = (unsigned)(u16)v0[j] | ((unsigned)(u16)v1[j] << 16);
                *(unsigned*)((char*)Vt + d * 128 + ((vkv * 2) ^ swz(d))) = val;
            }
        }
        __syncthreads();

        const bool active = (kv0 <= q0 + wave * 32 + 31);
        if (!active) continue;   // wave-uniform; all waves still hit next iter's barrier

        // ---- QK^T (swapped): S^T[kv][q], two 32-kv tiles ----
        f32x16 s0 = {}, s1 = {};
        #pragma unroll
        for (int kd = 0; kd < 4; kd++) {
            int r0 = l31, r1 = 32 + l31;
            short8 ka0 = *(const short8*)((const char*)Kt + r0 * 128 + ((kd * 32 + hA * 16) ^ swz(r0)));
            short8 ka1 = *(const short8*)((const char*)Kt + r1 * 128 + ((kd * 32 + hA * 16) ^ swz(r1)));
            s0 = __builtin_amdgcn_mfma_f32_32x32x16_bf16(ka0, qf[kd], s0, 0, 0, 0);
            s1 = __builtin_amdgcn_mfma_f32_32x32x16_bf16(ka1, qf[kd], s1, 0, 0, 0);
        }

        // ---- causal mask: gate vs the wave's MIN q-row ----
        if (kv0 + 63 > q0 + wave * 32) {
            #pragma unroll
            for (int r = 0; r < 16; r++) {
                int kvr = kv0 + ((r & 3) + 8 * (r >> 2) + 4 * hA);
                if (kvr > qg)      s0[r] = -1e30f;
                if (kvr + 32 > qg) s1[r] = -1e30f;
            }
        }

        // ---- online softmax: per-lane scalar m, defer-rescale (THR=8 in exp2 units) ----
        float pm = s0[0];
        #pragma unroll
        for (int r = 1; r < 16; r++) pm = fmaxf(pm, s0[r]);
        #pragma unroll
        for (int r = 0; r < 16; r++) pm = fmaxf(pm, s1[r]);
        pm = fmaxf(pm, __shfl_xor(pm, 32));
        float pms = pm * SCALE_L2E;
        if (__any(pms - ms > 8.0f)) {
            float msn = fmaxf(ms, pms);
            float alpha = exp2f(ms - msn);
            ms = msn;
            lsum *= alpha;
            #pragma unroll
            for (int r = 0; r < 16; r++) { o0[r] *= alpha; o1[r] *= alpha; }
        }

        // ---- P = exp2(s*scale - ms); row-sum in-register ----
        float part = 0.f;
        #pragma unroll
        for (int r = 0; r < 16; r++) {
            float p0 = exp2f(s0[r] * SCALE_L2E - ms);
            float p1 = exp2f(s1[r] * SCALE_L2E - ms);
            s0[r] = p0; s1[r] = p1;
            part += p0 + p1;
        }
        lsum += part + __shfl_xor(part, 32);

        // ---- P -> bf16 dwords (cvt_pk), 8 per 32-kv tile ----
        unsigned w0[8], w1[8];
        #pragma unroll
        for (int j = 0; j < 8; j++) {
            asm("v_cvt_pk_bf16_f32 %0, %1, %2" : "=v"(w0[j]) : "v"(s0[2 * j]), "v"(s0[2 * j + 1]));
            asm("v_cvt_pk_bf16_f32 %0, %1, %2" : "=v"(w1[j]) : "v"(s1[2 * j]), "v"(s1[2 * j + 1]));
        }

        // ---- PV (swapped): O^T += V^T · P^T; P^T B-frag built via permlane32_swap ----
        #define PV_TILE(W, ST)                                                              \
        {                                                                                   \
            _Pragma("unroll")                                                               \
            for (int kkl = 0; kkl < 2; kkl++) {                                             \
                unsigned a  = W[4 * kkl],     bsw = W[4 * kkl + 2];                         \
                unsigned a2 = W[4 * kkl + 1], b2  = W[4 * kkl + 3];                         \
                swap32(a, bsw); swap32(a2, b2);                                             \
                union { int4 i; short8 s; } u;                                              \
                u.i = make_int4((int)a, (int)a2, (int)bsw, (int)b2);                        \
                {                                                                           \
                    int row = l31;                                                          \
                    short8 va = *(const short8*)((const char*)Vt + row * 128                \
                                  + (((ST) * 64 + kkl * 32 + hA * 16) ^ swz(row)));         \
                    o0 = __builtin_amdgcn_mfma_f32_32x32x16_bf16(va, u.s, o0, 0, 0, 0);     \
                }                                                                           \
                {                                                                           \
                    int row = 32 + l31;                                                     \
                    short8 va = *(const short8*)((const char*)Vt + row * 128                \
                                  + (((ST) * 64 + kkl * 32 + hA * 16) ^ swz(row)));         \
                    o1 = __builtin_amdgcn_mfma_f32_32x32x16_bf16(va, u.s, o1, 0, 0, 0);     \
                }                                                                           \
            }                                                                               \
        }
        PV_TILE(w0, 0)
        PV_TILE(w1, 1)
        #undef PV_TILE
    }

    // ---- epilogue: normalize, transpose O^T -> O via LDS (once per block), store bf16 --
    __syncthreads();   // all tiles done reading Kt/Vt
    float rinv = 1.0f / lsum;
    u16* Ot = (wave < 2 ? Kt : Vt) + (wave & 1) * 2048;   // 32 rows x 64 d per wave (4KB)
    const int X = (l31 & 7) << 4;
    #pragma unroll
    for (int rq = 0; rq < 4; rq++) {
        u16x4 pk0, pk1;
        #pragma unroll
        for (int j = 0; j < 4; j++) {
            pk0[j] = f2bf(o0[4 * rq + j] * rinv);    // d = 8*rq + 4*hA + j
            pk1[j] = f2bf(o1[4 * rq + j] * rinv);    // d = 32 + 8*rq + 4*hA + j
        }
        *(u16x4*)((char*)Ot + l31 * 128 + ((16 * rq + 8 * hA) ^ X))      = pk0;
        *(u16x4*)((char*)Ot + l31 * 128 + ((64 + 16 * rq + 8 * hA) ^ X)) = pk1;
    }
    __syncthreads();
    #pragma unroll
    for (int p = 0; p < 4; p++) {
        int row = p * 8 + (lane >> 3);               // 0..31 within wave's tile
        int cc  = lane & 7;                          // 16B chunk (8 d-elems)
        short8 vv = *(const short8*)((const char*)Ot + row * 128
                      + ((cc * 16) ^ ((row & 7) << 4)));
        *(short8*)(y + (rowbase + q0 + wave * 32 + row) * E + h * 64 + cc * 8) = vv;
    }
}

// ---------------- launch ----------------
extern "C" void kernel_launch(void* const* d_in, const int* in_sizes, int n_in,
                              void* d_out, int out_size, void* d_ws, size_t ws_size,
                              hipStream_t stream) {
    const float* x     = (const float*)d_in[0];   // [8,1024,1024]
    const float* Wattn = (const float*)d_in[1];   // [1024,3072]
    const float* Wproj = (const float*)d_in[2];   // [1024,1024]
    float* out = (float*)d_out;                   // [8,1024,1024] fp32

    char* ws = (char*)d_ws;
    u16* buf0 = (u16*)ws;                                  // x_bf16, later y_bf16 (16.78 MB)
    u16* wT   = (u16*)(ws + 16777216);                     // W^T bf16 (6.29 MB, reused)
    u16* qkv  = (u16*)(ws + 16777216 + 6291456);           // [8192][3072] bf16 (50.3 MB)

    // x -> bf16
    k_conv_x<<<2048, 256, 0, stream>>>(x, buf0, 8388608 / 4);
    // W_attn^T -> bf16 [3072][1024]
    k_transpose_bf<<<dim3(3072 / 32, 1024 / 32), dim3(32, 8), 0, stream>>>(Wattn, wT, 1024, 3072);
    // qkv = x @ W_attn   (bf16 out): 256x256 tile, grid 12x32 = 384 wgs
    k_gemm_p<256, 256, true><<<dim3(3072 / 256, 8192 / 256), 512, 0, stream>>>(buf0, wT, qkv, 3072, 1024);
    // W_proj^T -> bf16 [1024][1024]
    k_transpose_bf<<<dim3(1024 / 32, 1024 / 32), dim3(32, 8), 0, stream>>>(Wproj, wT, 1024, 1024);
    // flash attention -> y (reuses buf0)
    k_attn<<<dim3(1024), 256, 0, stream>>>(qkv, buf0);
    // out = y @ W_proj  (fp32 out): 128x256 tile, grid 4x64 = 256 wgs
    k_gemm_p<128, 256, false><<<dim3(1024 / 256, 8192 / 128), 512, 0, stream>>>(buf0, wT, out, 1024, 1024);
}

// Round 6
// 146.243 us; speedup vs baseline: 1.0355x; 1.0355x over previous
//
#include <hip/hip_runtime.h>
#include <hip/hip_bf16.h>

typedef unsigned short u16;
typedef __attribute__((ext_vector_type(8))) short short8;
typedef __attribute__((ext_vector_type(4))) float f32x4;
typedef __attribute__((ext_vector_type(16))) float f32x16;
typedef __attribute__((ext_vector_type(4))) unsigned short u16x4;

#define DEVINL __device__ __forceinline__

DEVINL u16 f2bf(float f) {
    union { float f; unsigned u; } x; x.f = f;
    unsigned u = x.u;
    u += 0x7fffu + ((u >> 16) & 1u);   // round-to-nearest-even
    return (u16)(u >> 16);
}

DEVINL void gload_lds16(const void* g, void* l) {
    __builtin_amdgcn_global_load_lds(
        (const __attribute__((address_space(1))) unsigned*)g,
        (__attribute__((address_space(3))) unsigned*)l, 16, 0, 0);
}

// XOR swizzle for 128B-stride LDS rows: spreads 16B slots across banks.
DEVINL int swz(int row) { return (((row & 7) ^ ((row >> 3) & 7)) << 4); }

// v_permlane32_swap: after call, for lane<32: a=own a, b=partner's a;
// for lane>=32: a=partner's b, b=own b.
DEVINL void swap32(unsigned& a, unsigned& b) {
#if __has_builtin(__builtin_amdgcn_permlane32_swap)
    typedef __attribute__((ext_vector_type(2))) unsigned uv2;
    uv2 r = __builtin_amdgcn_permlane32_swap(a, b, false, false);
    a = r.x; b = r.y;
#else
    int h = ((int)(threadIdx.x & 63)) >> 5;
    unsigned pa = (unsigned)__shfl_xor((int)a, 32);
    unsigned pb = (unsigned)__shfl_xor((int)b, 32);
    unsigned na = h ? pb : a;
    unsigned nb = h ? b : pa;
    a = na; b = nb;
#endif
}

// ---------------- convert x (fp32 -> bf16), vectorized ----------------
__global__ void k_conv_x(const float* __restrict__ in, u16* __restrict__ out, int n4) {
    int i = blockIdx.x * blockDim.x + threadIdx.x;
    int stride = gridDim.x * blockDim.x;
    for (; i < n4; i += stride) {
        float4 v = ((const float4*)in)[i];
        u16x4 o;
        o.x = f2bf(v.x); o.y = f2bf(v.y); o.z = f2bf(v.z); o.w = f2bf(v.w);
        ((u16x4*)out)[i] = o;
    }
}

// ---------------- transpose + convert: in [R][C] fp32 -> out [C][R] bf16 ----------------
__global__ void k_transpose_bf(const float* __restrict__ in, u16* __restrict__ out, int R, int C) {
    __shared__ float t[32][33];
    int c0 = blockIdx.x * 32, r0 = blockIdx.y * 32;
    int tx = threadIdx.x, ty = threadIdx.y;
    #pragma unroll
    for (int j = 0; j < 32; j += 8)
        t[ty + j][tx] = in[(size_t)(r0 + ty + j) * C + c0 + tx];
    __syncthreads();
    #pragma unroll
    for (int j = 0; j < 32; j += 8)
        out[(size_t)(c0 + ty + j) * R + r0 + tx] = f2bf(t[tx][ty + j]);
}

// ---------------- GEMM: m201-style 8-phase schedule (4 phases per K-tile of 64) --------
// C[M][N] = A[M][K] @ BT[N][K]^T, bf16 in, bf16/f32 out.
// 512 threads = 8 waves (2M x 4N). Double-buffered LDS, per-phase interleave:
// {ds_read quadrant-subtile; stage 1-2 chunks; barrier; lgkmcnt(0); 16 MFMA; barrier}.
// vmcnt(ACH+2) ONCE per K-tile (3 chunk-groups in flight), never 0 in steady state.
#define DO_MFMA(H, J)                                                            \
    __builtin_amdgcn_s_barrier();                                                \
    asm volatile("s_waitcnt lgkmcnt(0)" ::: "memory");                           \
    __builtin_amdgcn_sched_barrier(0);                                           \
    __builtin_amdgcn_s_setprio(1);                                               \
    _Pragma("unroll")                                                            \
    for (int m = 0; m < MFh; m++)                                                \
        _Pragma("unroll")                                                        \
        for (int n = 0; n < NFh; n++)                                            \
            _Pragma("unroll")                                                    \
            for (int kk = 0; kk < 2; kk++)                                       \
                acc[(H) * MFh + m][(J) * NFh + n] =                              \
                    __builtin_amdgcn_mfma_f32_16x16x32_bf16(                     \
                        afr[m][kk], bfr[(J) * NFh + n][kk],                      \
                        acc[(H) * MFh + m][(J) * NFh + n], 0, 0, 0);             \
    __builtin_amdgcn_s_setprio(0);

template<int BM, int BN, bool OUT_BF16>
__global__ __launch_bounds__(512, 2)
void k_gemm8(const u16* __restrict__ A, const u16* __restrict__ BT,
             void* __restrict__ C, int N, int K) {
    constexpr int MF  = BM / 32;      // per-wave M frags (WM=2): 8 or 4
    constexpr int NF  = BN / 64;      // per-wave N frags (WN=4): 4
    constexpr int MFh = MF / 2;
    constexpr int NFh = NF / 2;
    constexpr int ACH = BM / 64;      // A 8KB chunks per K-tile: 4 or 2
    constexpr int TB  = (ACH + 4) * 8192;
    __shared__ char lds[2 * TB];

    const int tid  = threadIdx.x;
    const int lane = tid & 63;
    const int lo   = lane & 15;
    const int hi   = lane >> 4;
    const int wave = tid >> 6;
    const int wm   = wave >> 2;
    const int wn   = wave & 3;

    // XCD-aware bijective block swizzle (nwg % 8 == 0 for our grids)
    const int gx   = gridDim.x;
    const int nwg  = gx * gridDim.y;
    const int orig = blockIdx.y * gx + blockIdx.x;
    const int wg   = (orig & 7) * (nwg >> 3) + (orig >> 3);
    const long row0 = (long)(wg / gx) * BM;
    const long col0 = (long)(wg % gx) * BN;

    const int NT = K >> 6;            // BK = 64

    const int srow = tid >> 3;                         // staging row within chunk
    const int gsb  = ((tid & 7) ^ (srow & 7)) << 4;    // pre-swizzled source byte

    auto stA = [&](int c, int t) {
        gload_lds16((const char*)(A + (row0 + c * 64 + srow) * (size_t)K + t * 64) + gsb,
                    lds + (t & 1) * TB + c * 8192 + tid * 16);
    };
    auto stB = [&](int c, int t) {
        gload_lds16((const char*)(BT + (col0 + c * 64 + srow) * (size_t)K + t * 64) + gsb,
                    lds + (t & 1) * TB + (ACH + c) * 8192 + tid * 16);
    };

    f32x4 acc[MF][NF] = {};
    short8 afr[MFh][2], bfr[NF][2];

    const int xsw  = (lo & 7) << 4;
    const int aRow = wm * (BM / 2) + lo;
    const int bRow = wn * 64 + lo;

    // ---- prologue: tile 0 fully, tile 1 minus B2,B3 ----
    #pragma unroll
    for (int c = 0; c < ACH; c++) stA(c, 0);
    #pragma unroll
    for (int c = 0; c < 4; c++) stB(c, 0);
    #pragma unroll
    for (int c = 0; c < ACH; c++) stA(c, 1);
    stB(0, 1); stB(1, 1);
    if constexpr (ACH == 4) asm volatile("s_waitcnt vmcnt(6)" ::: "memory");
    else                    asm volatile("s_waitcnt vmcnt(4)" ::: "memory");
    __builtin_amdgcn_s_barrier();

    for (int t = 0; t < NT; t++) {
        const char* ab = lds + (t & 1) * TB;
        const char* bb = ab + ACH * 8192;

        // ---------- phase 0: read a[0..MFh-1], b[0..NFh-1]; stage B2,B3(t+1) ----------
        #pragma unroll
        for (int m = 0; m < MFh; m++) {
            int r = aRow + m * 16;
            #pragma unroll
            for (int kk = 0; kk < 2; kk++)
                afr[m][kk] = *(const short8*)(ab + r * 128 + ((kk * 64 + hi * 16) ^ xsw));
        }
        #pragma unroll
        for (int n = 0; n < NFh; n++) {
            int r = bRow + n * 16;
            #pragma unroll
            for (int kk = 0; kk < 2; kk++)
                bfr[n][kk] = *(const short8*)(bb + r * 128 + ((kk * 64 + hi * 16) ^ xsw));
        }
        if (t + 1 < NT) { stB(2, t + 1); stB(3, t + 1); }
        DO_MFMA(0, 0)
        __builtin_amdgcn_s_barrier();

        // ---------- phase 1: read b[NFh..NF-1]; stage B0,B1(t+2) ----------
        #pragma unroll
        for (int n = NFh; n < NF; n++) {
            int r = bRow + n * 16;
            #pragma unroll
            for (int kk = 0; kk < 2; kk++)
                bfr[n][kk] = *(const short8*)(bb + r * 128 + ((kk * 64 + hi * 16) ^ xsw));
        }
        if (t + 2 < NT) { stB(0, t + 2); stB(1, t + 2); }
        DO_MFMA(0, 1)
        __builtin_amdgcn_s_barrier();

        // ---------- phase 2: read a[MFh..MF-1]; stage A-even(t+2) ----------
        #pragma unroll
        for (int m = 0; m < MFh; m++) {
            int r = aRow + (MFh + m) * 16;
            #pragma unroll
            for (int kk = 0; kk < 2; kk++)
                afr[m][kk] = *(const short8*)(ab + r * 128 + ((kk * 64 + hi * 16) ^ xsw));
        }
        if (t + 2 < NT) { stA(0, t + 2); if constexpr (ACH == 4) stA(2, t + 2); }
        DO_MFMA(1, 0)
        __builtin_amdgcn_s_barrier();

        // ---------- phase 3: stage A-odd(t+2); K-tile boundary vmcnt ----------
        if (t + 2 < NT) { stA(1, t + 2); if constexpr (ACH == 4) stA(3, t + 2); }
        DO_MFMA(1, 1)
        if (t + 2 < NT) {
            if constexpr (ACH == 4) asm volatile("s_waitcnt vmcnt(6)" ::: "memory");
            else                    asm volatile("s_waitcnt vmcnt(4)" ::: "memory");
        } else {
            asm volatile("s_waitcnt vmcnt(0)" ::: "memory");
        }
        __builtin_amdgcn_s_barrier();
    }

    // ---- epilogue ----
    #pragma unroll
    for (int m = 0; m < MF; m++)
        #pragma unroll
        for (int n = 0; n < NF; n++)
            #pragma unroll
            for (int r = 0; r < 4; r++) {
                long row = row0 + wm * (BM / 2) + m * 16 + hi * 4 + r;
                long col = col0 + wn * 64 + n * 16 + lo;
                if constexpr (OUT_BF16)
                    ((u16*)C)[row * (size_t)N + col] = f2bf(acc[m][n][r]);
                else
                    ((float*)C)[row * (size_t)N + col] = acc[m][n][r];
            }
}

// ---------------- Flash attention v3: swapped-operand 32x32, in-register softmax --------
// grid: 1024 blocks (8 qi x 128 bh), longest-first. Block = 4 waves x 32 q-rows = 128 q.
#define SCALE_L2E 0.18033688011112042f  // (1/sqrt(64)) * log2(e)

__global__ __launch_bounds__(256, 2)
void k_attn(const u16* __restrict__ qkv, u16* __restrict__ y) {
    constexpr int S = 1024, E = 1024, TE = 3072;
    __shared__ u16 Kt[64 * 64];   // [kv][d], swizzled rows (128B)
    __shared__ u16 Vt[64 * 64];   // [d][kv], swizzled rows (128B)

    const int tid  = threadIdx.x;
    const int lane = tid & 63;
    const int l31  = lane & 31;
    const int hA   = lane >> 5;
    const int wave = tid >> 6;

    const int qi = 7 - (int)(blockIdx.x >> 7);   // longest first
    const int bh = blockIdx.x & 127;
    const int b  = bh >> 4;
    const int h  = bh & 15;
    const int q0 = qi * 128;
    const size_t rowbase = (size_t)b * S;
    const int qg = q0 + wave * 32 + l31;         // this lane's q-row

    short8 qf[4];
    {
        const u16* qp = qkv + (rowbase + qg) * TE + h * 64 + hA * 8;
        #pragma unroll
        for (int kd = 0; kd < 4; kd++) qf[kd] = *(const short8*)(qp + kd * 16);
    }

    f32x16 o0 = {}, o1 = {};
    float ms = -1e30f, lsum = 0.f;

    const int kr0 = (wave << 3) + (lane >> 3);
    const int kcb = (lane & 7) * 16;
    const int vkv = (tid >> 3) * 2;
    const int vdc = (tid & 7) * 8;

    const int ntiles = 2 * qi + 2;
    for (int t = 0; t < ntiles; ++t) {
        const int kv0 = t * 64;
        __syncthreads();
        #pragma unroll
        for (int it = 0; it < 2; it++) {
            int r = kr0 + it * 32;
            const char* src = (const char*)qkv
                + (((rowbase + kv0 + r) * TE + E + h * 64) << 1) + (kcb ^ swz(r));
            gload_lds16(src, (char*)Kt + wave * 1024 + it * 4096);
        }
        {
            const u16* vsrc = qkv + (rowbase + kv0 + vkv) * TE + 2 * E + h * 64 + vdc;
            short8 v0 = *(const short8*)vsrc;
            short8 v1 = *(const short8*)(vsrc + TE);
            #pragma unroll
            for (int j = 0; j < 8; j++) {
                int d = vdc + j;
                unsigned val = (unsigned)(u16)v0[j] | ((unsigned)(u16)v1[j] << 16);
                *(unsigned*)((char*)Vt + d * 128 + ((vkv * 2) ^ swz(d))) = val;
            }
        }
        __syncthreads();

        const bool active = (kv0 <= q0 + wave * 32 + 31);
        if (!active) continue;

        f32x16 s0 = {}, s1 = {};
        #pragma unroll
        for (int kd = 0; kd < 4; kd++) {
            int r0 = l31, r1 = 32 + l31;
            short8 ka0 = *(const short8*)((const char*)Kt + r0 * 128 + ((kd * 32 + hA * 16) ^ swz(r0)));
            short8 ka1 = *(const short8*)((const char*)Kt + r1 * 128 + ((kd * 32 + hA * 16) ^ swz(r1)));
            s0 = __builtin_amdgcn_mfma_f32_32x32x16_bf16(ka0, qf[kd], s0, 0, 0, 0);
            s1 = __builtin_amdgcn_mfma_f32_32x32x16_bf16(ka1, qf[kd], s1, 0, 0, 0);
        }

        if (kv0 + 63 > q0 + wave * 32) {
            #pragma unroll
            for (int r = 0; r < 16; r++) {
                int kvr = kv0 + ((r & 3) + 8 * (r >> 2) + 4 * hA);
                if (kvr > qg)      s0[r] = -1e30f;
                if (kvr + 32 > qg) s1[r] = -1e30f;
            }
        }

        float pm = s0[0];
        #pragma unroll
        for (int r = 1; r < 16; r++) pm = fmaxf(pm, s0[r]);
        #pragma unroll
        for (int r = 0; r < 16; r++) pm = fmaxf(pm, s1[r]);
        pm = fmaxf(pm, __shfl_xor(pm, 32));
        float pms = pm * SCALE_L2E;
        if (__any(pms - ms > 8.0f)) {
            float msn = fmaxf(ms, pms);
            float alpha = exp2f(ms - msn);
            ms = msn;
            lsum *= alpha;
            #pragma unroll
            for (int r = 0; r < 16; r++) { o0[r] *= alpha; o1[r] *= alpha; }
        }

        float part = 0.f;
        #pragma unroll
        for (int r = 0; r < 16; r++) {
            float p0 = exp2f(s0[r] * SCALE_L2E - ms);
            float p1 = exp2f(s1[r] * SCALE_L2E - ms);
            s0[r] = p0; s1[r] = p1;
            part += p0 + p1;
        }
        lsum += part + __shfl_xor(part, 32);

        unsigned w0[8], w1[8];
        #pragma unroll
        for (int j = 0; j < 8; j++) {
            asm("v_cvt_pk_bf16_f32 %0, %1, %2" : "=v"(w0[j]) : "v"(s0[2 * j]), "v"(s0[2 * j + 1]));
            asm("v_cvt_pk_bf16_f32 %0, %1, %2" : "=v"(w1[j]) : "v"(s1[2 * j]), "v"(s1[2 * j + 1]));
        }

        #define PV_TILE(W, ST)                                                              \
        {                                                                                   \
            _Pragma("unroll")                                                               \
            for (int kkl = 0; kkl < 2; kkl++) {                                             \
                unsigned a  = W[4 * kkl],     bsw = W[4 * kkl + 2];                         \
                unsigned a2 = W[4 * kkl + 1], b2  = W[4 * kkl + 3];                         \
                swap32(a, bsw); swap32(a2, b2);                                             \
                union { int4 i; short8 s; } u;                                              \
                u.i = make_int4((int)a, (int)a2, (int)bsw, (int)b2);                        \
                {                                                                           \
                    int row = l31;                                                          \
                    short8 va = *(const short8*)((const char*)Vt + row * 128                \
                                  + (((ST) * 64 + kkl * 32 + hA * 16) ^ swz(row)));         \
                    o0 = __builtin_amdgcn_mfma_f32_32x32x16_bf16(va, u.s, o0, 0, 0, 0);     \
                }                                                                           \
                {                                                                           \
                    int row = 32 + l31;                                                     \
                    short8 va = *(const short8*)((const char*)Vt + row * 128                \
                                  + (((ST) * 64 + kkl * 32 + hA * 16) ^ swz(row)));         \
                    o1 = __builtin_amdgcn_mfma_f32_32x32x16_bf16(va, u.s, o1, 0, 0, 0);     \
                }                                                                           \
            }                                                                               \
        }
        PV_TILE(w0, 0)
        PV_TILE(w1, 1)
        #undef PV_TILE
    }

    __syncthreads();
    float rinv = 1.0f / lsum;
    u16* Ot = (wave < 2 ? Kt : Vt) + (wave & 1) * 2048;
    const int X = (l31 & 7) << 4;
    #pragma unroll
    for (int rq = 0; rq < 4; rq++) {
        u16x4 pk0, pk1;
        #pragma unroll
        for (int j = 0; j < 4; j++) {
            pk0[j] = f2bf(o0[4 * rq + j] * rinv);
            pk1[j] = f2bf(o1[4 * rq + j] * rinv);
        }
        *(u16x4*)((char*)Ot + l31 * 128 + ((16 * rq + 8 * hA) ^ X))      = pk0;
        *(u16x4*)((char*)Ot + l31 * 128 + ((64 + 16 * rq + 8 * hA) ^ X)) = pk1;
    }
    __syncthreads();
    #pragma unroll
    for (int p = 0; p < 4; p++) {
        int row = p * 8 + (lane >> 3);
        int cc  = lane & 7;
        short8 vv = *(const short8*)((const char*)Ot + row * 128
                      + ((cc * 16) ^ ((row & 7) << 4)));
        *(short8*)(y + (rowbase + q0 + wave * 32 + row) * E + h * 64 + cc * 8) = vv;
    }
}

// ---------------- launch ----------------
extern "C" void kernel_launch(void* const* d_in, const int* in_sizes, int n_in,
                              void* d_out, int out_size, void* d_ws, size_t ws_size,
                              hipStream_t stream) {
    const float* x     = (const float*)d_in[0];   // [8,1024,1024]
    const float* Wattn = (const float*)d_in[1];   // [1024,3072]
    const float* Wproj = (const float*)d_in[2];   // [1024,1024]
    float* out = (float*)d_out;                   // [8,1024,1024] fp32

    char* ws = (char*)d_ws;
    u16* buf0 = (u16*)ws;                                  // x_bf16, later y_bf16 (16.78 MB)
    u16* wT   = (u16*)(ws + 16777216);                     // W^T bf16 (6.29 MB, reused)
    u16* qkv  = (u16*)(ws + 16777216 + 6291456);           // [8192][3072] bf16 (50.3 MB)

    // x -> bf16
    k_conv_x<<<2048, 256, 0, stream>>>(x, buf0, 8388608 / 4);
    // W_attn^T -> bf16 [3072][1024]
    k_transpose_bf<<<dim3(3072 / 32, 1024 / 32), dim3(32, 8), 0, stream>>>(Wattn, wT, 1024, 3072);
    // qkv = x @ W_attn   (bf16 out): 256x256 8-phase, grid 12x32 = 384 wgs
    k_gemm8<256, 256, true><<<dim3(3072 / 256, 8192 / 256), 512, 0, stream>>>(buf0, wT, qkv, 3072, 1024);
    // W_proj^T -> bf16 [1024][1024]
    k_transpose_bf<<<dim3(1024 / 32, 1024 / 32), dim3(32, 8), 0, stream>>>(Wproj, wT, 1024, 1024);
    // flash attention -> y (reuses buf0)
    k_attn<<<dim3(1024), 256, 0, stream>>>(qkv, buf0);
    // out = y @ W_proj  (fp32 out): 128x256 8-phase, grid 4x64 = 256 wgs
    k_gemm8<128, 256, false><<<dim3(1024 / 256, 8192 / 128), 512, 0, stream>>>(buf0, wT, out, 1024, 1024);
}

// Round 7
// 146.050 us; speedup vs baseline: 1.0368x; 1.0013x over previous
//
#include <hip/hip_runtime.h>
#include <hip/hip_bf16.h>

typedef unsigned short u16;
typedef __attribute__((ext_vector_type(8))) short short8;
typedef __attribute__((ext_vector_type(4))) float f32x4;
typedef __attribute__((ext_vector_type(16))) float f32x16;
typedef __attribute__((ext_vector_type(4))) unsigned short u16x4;

#define DEVINL __device__ __forceinline__

DEVINL u16 f2bf(float f) {
    union { float f; unsigned u; } x; x.f = f;
    unsigned u = x.u;
    u += 0x7fffu + ((u >> 16) & 1u);   // round-to-nearest-even
    return (u16)(u >> 16);
}

DEVINL void gload_lds16(const void* g, void* l) {
    __builtin_amdgcn_global_load_lds(
        (const __attribute__((address_space(1))) unsigned*)g,
        (__attribute__((address_space(3))) unsigned*)l, 16, 0, 0);
}

// XOR swizzle for 128B-stride LDS rows: spreads 16B slots across banks.
DEVINL int swz(int row) { return (((row & 7) ^ ((row >> 3) & 7)) << 4); }

// v_permlane32_swap: after call, for lane<32: a=own a, b=partner's a;
// for lane>=32: a=partner's b, b=own b.
DEVINL void swap32(unsigned& a, unsigned& b) {
#if __has_builtin(__builtin_amdgcn_permlane32_swap)
    typedef __attribute__((ext_vector_type(2))) unsigned uv2;
    uv2 r = __builtin_amdgcn_permlane32_swap(a, b, false, false);
    a = r.x; b = r.y;
#else
    int h = ((int)(threadIdx.x & 63)) >> 5;
    unsigned pa = (unsigned)__shfl_xor((int)a, 32);
    unsigned pb = (unsigned)__shfl_xor((int)b, 32);
    unsigned na = h ? pb : a;
    unsigned nb = h ? b : pa;
    a = na; b = nb;
#endif
}

// ---------------- convert x (fp32 -> bf16), vectorized ----------------
__global__ void k_conv_x(const float* __restrict__ in, u16* __restrict__ out, int n4) {
    int i = blockIdx.x * blockDim.x + threadIdx.x;
    int stride = gridDim.x * blockDim.x;
    for (; i < n4; i += stride) {
        float4 v = ((const float4*)in)[i];
        u16x4 o;
        o.x = f2bf(v.x); o.y = f2bf(v.y); o.z = f2bf(v.z); o.w = f2bf(v.w);
        ((u16x4*)out)[i] = o;
    }
}

// ---------------- transpose + convert: in [R][C] fp32 -> out [C][R] bf16 ----------------
__global__ void k_transpose_bf(const float* __restrict__ in, u16* __restrict__ out, int R, int C) {
    __shared__ float t[32][33];
    int c0 = blockIdx.x * 32, r0 = blockIdx.y * 32;
    int tx = threadIdx.x, ty = threadIdx.y;
    #pragma unroll
    for (int j = 0; j < 32; j += 8)
        t[ty + j][tx] = in[(size_t)(r0 + ty + j) * C + c0 + tx];
    __syncthreads();
    #pragma unroll
    for (int j = 0; j < 32; j += 8)
        out[(size_t)(c0 + ty + j) * R + r0 + tx] = f2bf(t[tx][ty + j]);
}

// ---------------- GEMM: 8-phase schedule with REGISTER-double-buffered fragments --------
// C[M][N] = A[M][K] @ BT[N][K]^T, bf16 in, bf16/f32 out.
// 512 threads = 8 waves (2M x 4N). Double-buffered LDS; per phase:
// {ds_read own subtile into its OWN register set; stage chunks; barrier; lgkmcnt(0);
//  16 MFMA (setprio); barrier}. Fragment sets alternate (afrA/afrB, bfr01/bfr23) so no
// phase writes registers a previous phase's in-flight MFMAs still read (WAR-free).
#define DO_MFMA(AF, BF, H, J)                                                    \
    __builtin_amdgcn_s_barrier();                                                \
    asm volatile("s_waitcnt lgkmcnt(0)" ::: "memory");                           \
    __builtin_amdgcn_sched_barrier(0);                                           \
    __builtin_amdgcn_s_setprio(1);                                               \
    _Pragma("unroll")                                                            \
    for (int m = 0; m < MFh; m++)                                                \
        _Pragma("unroll")                                                        \
        for (int n = 0; n < NFh; n++)                                            \
            _Pragma("unroll")                                                    \
            for (int kk = 0; kk < 2; kk++)                                       \
                acc[(H) * MFh + m][(J) * NFh + n] =                              \
                    __builtin_amdgcn_mfma_f32_16x16x32_bf16(                     \
                        AF[m][kk], BF[n][kk],                                    \
                        acc[(H) * MFh + m][(J) * NFh + n], 0, 0, 0);             \
    __builtin_amdgcn_s_setprio(0);

template<int BM, int BN, bool OUT_BF16>
__global__ __launch_bounds__(512, 2)
void k_gemm8(const u16* __restrict__ A, const u16* __restrict__ BT,
             void* __restrict__ C, int N, int K) {
    constexpr int MF  = BM / 32;      // per-wave M frags (WM=2): 8 or 4
    constexpr int NF  = BN / 64;      // per-wave N frags (WN=4): 4
    constexpr int MFh = MF / 2;
    constexpr int NFh = NF / 2;
    constexpr int ACH = BM / 64;      // A 8KB chunks per K-tile: 4 or 2
    constexpr int TB  = (ACH + 4) * 8192;
    __shared__ char lds[2 * TB];

    const int tid  = threadIdx.x;
    const int lane = tid & 63;
    const int lo   = lane & 15;
    const int hi   = lane >> 4;
    const int wave = tid >> 6;
    const int wm   = wave >> 2;
    const int wn   = wave & 3;

    // XCD-aware bijective block swizzle (nwg % 8 == 0 for our grids)
    const int gx   = gridDim.x;
    const int nwg  = gx * gridDim.y;
    const int orig = blockIdx.y * gx + blockIdx.x;
    const int wg   = (orig & 7) * (nwg >> 3) + (orig >> 3);
    const long row0 = (long)(wg / gx) * BM;
    const long col0 = (long)(wg % gx) * BN;

    const int NT = K >> 6;            // BK = 64

    const int srow = tid >> 3;                         // staging row within chunk
    const int gsb  = ((tid & 7) ^ (srow & 7)) << 4;    // pre-swizzled source byte

    auto stA = [&](int c, int t) {
        gload_lds16((const char*)(A + (row0 + c * 64 + srow) * (size_t)K + t * 64) + gsb,
                    lds + (t & 1) * TB + c * 8192 + tid * 16);
    };
    auto stB = [&](int c, int t) {
        gload_lds16((const char*)(BT + (col0 + c * 64 + srow) * (size_t)K + t * 64) + gsb,
                    lds + (t & 1) * TB + (ACH + c) * 8192 + tid * 16);
    };

    f32x4 acc[MF][NF] = {};
    // register-double-buffered fragments: each written in its own phase only
    short8 afrA[MFh][2], afrB[MFh][2], bfr01[NFh][2], bfr23[NFh][2];

    const int xsw  = (lo & 7) << 4;
    const int aRow = wm * (BM / 2) + lo;
    const int bRow = wn * 64 + lo;

    // ---- prologue: tile 0 fully, tile 1 minus B2,B3 ----
    #pragma unroll
    for (int c = 0; c < ACH; c++) stA(c, 0);
    #pragma unroll
    for (int c = 0; c < 4; c++) stB(c, 0);
    #pragma unroll
    for (int c = 0; c < ACH; c++) stA(c, 1);
    stB(0, 1); stB(1, 1);
    if constexpr (ACH == 4) asm volatile("s_waitcnt vmcnt(6)" ::: "memory");
    else                    asm volatile("s_waitcnt vmcnt(4)" ::: "memory");
    __builtin_amdgcn_s_barrier();

    for (int t = 0; t < NT; t++) {
        const char* ab = lds + (t & 1) * TB;
        const char* bb = ab + ACH * 8192;

        // ---------- phase 0: read afrA + bfr01; stage B2,B3(t+1) ----------
        #pragma unroll
        for (int m = 0; m < MFh; m++) {
            int r = aRow + m * 16;
            #pragma unroll
            for (int kk = 0; kk < 2; kk++)
                afrA[m][kk] = *(const short8*)(ab + r * 128 + ((kk * 64 + hi * 16) ^ xsw));
        }
        #pragma unroll
        for (int n = 0; n < NFh; n++) {
            int r = bRow + n * 16;
            #pragma unroll
            for (int kk = 0; kk < 2; kk++)
                bfr01[n][kk] = *(const short8*)(bb + r * 128 + ((kk * 64 + hi * 16) ^ xsw));
        }
        if (t + 1 < NT) { stB(2, t + 1); stB(3, t + 1); }
        DO_MFMA(afrA, bfr01, 0, 0)
        __builtin_amdgcn_s_barrier();

        // ---------- phase 1: read bfr23; stage B0,B1(t+2) ----------
        #pragma unroll
        for (int n = 0; n < NFh; n++) {
            int r = bRow + (NFh + n) * 16;
            #pragma unroll
            for (int kk = 0; kk < 2; kk++)
                bfr23[n][kk] = *(const short8*)(bb + r * 128 + ((kk * 64 + hi * 16) ^ xsw));
        }
        if (t + 2 < NT) { stB(0, t + 2); stB(1, t + 2); }
        DO_MFMA(afrA, bfr23, 0, 1)
        __builtin_amdgcn_s_barrier();

        // ---------- phase 2: read afrB; stage A-even(t+2) ----------
        #pragma unroll
        for (int m = 0; m < MFh; m++) {
            int r = aRow + (MFh + m) * 16;
            #pragma unroll
            for (int kk = 0; kk < 2; kk++)
                afrB[m][kk] = *(const short8*)(ab + r * 128 + ((kk * 64 + hi * 16) ^ xsw));
        }
        if (t + 2 < NT) { stA(0, t + 2); if constexpr (ACH == 4) stA(2, t + 2); }
        DO_MFMA(afrB, bfr01, 1, 0)
        __builtin_amdgcn_s_barrier();

        // ---------- phase 3: stage A-odd(t+2); K-tile boundary vmcnt ----------
        if (t + 2 < NT) { stA(1, t + 2); if constexpr (ACH == 4) stA(3, t + 2); }
        DO_MFMA(afrB, bfr23, 1, 1)
        if (t + 2 < NT) {
            if constexpr (ACH == 4) asm volatile("s_waitcnt vmcnt(6)" ::: "memory");
            else                    asm volatile("s_waitcnt vmcnt(4)" ::: "memory");
        } else {
            asm volatile("s_waitcnt vmcnt(0)" ::: "memory");
        }
        __builtin_amdgcn_s_barrier();
    }

    // ---- epilogue ----
    #pragma unroll
    for (int m = 0; m < MF; m++)
        #pragma unroll
        for (int n = 0; n < NF; n++)
            #pragma unroll
            for (int r = 0; r < 4; r++) {
                long row = row0 + wm * (BM / 2) + m * 16 + hi * 4 + r;
                long col = col0 + wn * 64 + n * 16 + lo;
                if constexpr (OUT_BF16)
                    ((u16*)C)[row * (size_t)N + col] = f2bf(acc[m][n][r]);
                else
                    ((float*)C)[row * (size_t)N + col] = acc[m][n][r];
            }
}

// ---------------- Flash attention v3: swapped-operand 32x32, in-register softmax --------
// grid: 1024 blocks (8 qi x 128 bh), longest-first. Block = 4 waves x 32 q-rows = 128 q.
#define SCALE_L2E 0.18033688011112042f  // (1/sqrt(64)) * log2(e)

__global__ __launch_bounds__(256, 2)
void k_attn(const u16* __restrict__ qkv, u16* __restrict__ y) {
    constexpr int S = 1024, E = 1024, TE = 3072;
    __shared__ u16 Kt[64 * 64];   // [kv][d], swizzled rows (128B)
    __shared__ u16 Vt[64 * 64];   // [d][kv], swizzled rows (128B)

    const int tid  = threadIdx.x;
    const int lane = tid & 63;
    const int l31  = lane & 31;
    const int hA   = lane >> 5;
    const int wave = tid >> 6;

    const int qi = 7 - (int)(blockIdx.x >> 7);   // longest first
    const int bh = blockIdx.x & 127;
    const int b  = bh >> 4;
    const int h  = bh & 15;
    const int q0 = qi * 128;
    const size_t rowbase = (size_t)b * S;
    const int qg = q0 + wave * 32 + l31;         // this lane's q-row

    short8 qf[4];
    {
        const u16* qp = qkv + (rowbase + qg) * TE + h * 64 + hA * 8;
        #pragma unroll
        for (int kd = 0; kd < 4; kd++) qf[kd] = *(const short8*)(qp + kd * 16);
    }

    f32x16 o0 = {}, o1 = {};
    float ms = -1e30f, lsum = 0.f;

    const int kr0 = (wave << 3) + (lane >> 3);
    const int kcb = (lane & 7) * 16;
    const int vkv = (tid >> 3) * 2;
    const int vdc = (tid & 7) * 8;

    const int ntiles = 2 * qi + 2;
    for (int t = 0; t < ntiles; ++t) {
        const int kv0 = t * 64;
        __syncthreads();
        #pragma unroll
        for (int it = 0; it < 2; it++) {
            int r = kr0 + it * 32;
            const char* src = (const char*)qkv
                + (((rowbase + kv0 + r) * TE + E + h * 64) << 1) + (kcb ^ swz(r));
            gload_lds16(src, (char*)Kt + wave * 1024 + it * 4096);
        }
        {
            const u16* vsrc = qkv + (rowbase + kv0 + vkv) * TE + 2 * E + h * 64 + vdc;
            short8 v0 = *(const short8*)vsrc;
            short8 v1 = *(const short8*)(vsrc + TE);
            #pragma unroll
            for (int j = 0; j < 8; j++) {
                int d = vdc + j;
                unsigned val = (unsigned)(u16)v0[j] | ((unsigned)(u16)v1[j] << 16);
                *(unsigned*)((char*)Vt + d * 128 + ((vkv * 2) ^ swz(d))) = val;
            }
        }
        __syncthreads();

        const bool active = (kv0 <= q0 + wave * 32 + 31);
        if (!active) continue;

        f32x16 s0 = {}, s1 = {};
        #pragma unroll
        for (int kd = 0; kd < 4; kd++) {
            int r0 = l31, r1 = 32 + l31;
            short8 ka0 = *(const short8*)((const char*)Kt + r0 * 128 + ((kd * 32 + hA * 16) ^ swz(r0)));
            short8 ka1 = *(const short8*)((const char*)Kt + r1 * 128 + ((kd * 32 + hA * 16) ^ swz(r1)));
            s0 = __builtin_amdgcn_mfma_f32_32x32x16_bf16(ka0, qf[kd], s0, 0, 0, 0);
            s1 = __builtin_amdgcn_mfma_f32_32x32x16_bf16(ka1, qf[kd], s1, 0, 0, 0);
        }

        if (kv0 + 63 > q0 + wave * 32) {
            #pragma unroll
            for (int r = 0; r < 16; r++) {
                int kvr = kv0 + ((r & 3) + 8 * (r >> 2) + 4 * hA);
                if (kvr > qg)      s0[r] = -1e30f;
                if (kvr + 32 > qg) s1[r] = -1e30f;
            }
        }

        float pm = s0[0];
        #pragma unroll
        for (int r = 1; r < 16; r++) pm = fmaxf(pm, s0[r]);
        #pragma unroll
        for (int r = 0; r < 16; r++) pm = fmaxf(pm, s1[r]);
        pm = fmaxf(pm, __shfl_xor(pm, 32));
        float pms = pm * SCALE_L2E;
        if (__any(pms - ms > 8.0f)) {
            float msn = fmaxf(ms, pms);
            float alpha = exp2f(ms - msn);
            ms = msn;
            lsum *= alpha;
            #pragma unroll
            for (int r = 0; r < 16; r++) { o0[r] *= alpha; o1[r] *= alpha; }
        }

        float part = 0.f;
        #pragma unroll
        for (int r = 0; r < 16; r++) {
            float p0 = exp2f(s0[r] * SCALE_L2E - ms);
            float p1 = exp2f(s1[r] * SCALE_L2E - ms);
            s0[r] = p0; s1[r] = p1;
            part += p0 + p1;
        }
        lsum += part + __shfl_xor(part, 32);

        unsigned w0[8], w1[8];
        #pragma unroll
        for (int j = 0; j < 8; j++) {
            asm("v_cvt_pk_bf16_f32 %0, %1, %2" : "=v"(w0[j]) : "v"(s0[2 * j]), "v"(s0[2 * j + 1]));
            asm("v_cvt_pk_bf16_f32 %0, %1, %2" : "=v"(w1[j]) : "v"(s1[2 * j]), "v"(s1[2 * j + 1]));
        }

        #define PV_TILE(W, ST)                                                              \
        {                                                                                   \
            _Pragma("unroll")                                                               \
            for (int kkl = 0; kkl < 2; kkl++) {                                             \
                unsigned a  = W[4 * kkl],     bsw = W[4 * kkl + 2];                         \
                unsigned a2 = W[4 * kkl + 1], b2  = W[4 * kkl + 3];                         \
                swap32(a, bsw); swap32(a2, b2);                                             \
                union { int4 i; short8 s; } u;                                              \
                u.i = make_int4((int)a, (int)a2, (int)bsw, (int)b2);                        \
                {                                                                           \
                    int row = l31;                                                          \
                    short8 va = *(const short8*)((const char*)Vt + row * 128                \
                                  + (((ST) * 64 + kkl * 32 + hA * 16) ^ swz(row)));         \
                    o0 = __builtin_amdgcn_mfma_f32_32x32x16_bf16(va, u.s, o0, 0, 0, 0);     \
                }                                                                           \
                {                                                                           \
                    int row = 32 + l31;                                                     \
                    short8 va = *(const short8*)((const char*)Vt + row * 128                \
                                  + (((ST) * 64 + kkl * 32 + hA * 16) ^ swz(row)));         \
                    o1 = __builtin_amdgcn_mfma_f32_32x32x16_bf16(va, u.s, o1, 0, 0, 0);     \
                }                                                                           \
            }                                                                               \
        }
        PV_TILE(w0, 0)
        PV_TILE(w1, 1)
        #undef PV_TILE
    }

    __syncthreads();
    float rinv = 1.0f / lsum;
    u16* Ot = (wave < 2 ? Kt : Vt) + (wave & 1) * 2048;
    const int X = (l31 & 7) << 4;
    #pragma unroll
    for (int rq = 0; rq < 4; rq++) {
        u16x4 pk0, pk1;
        #pragma unroll
        for (int j = 0; j < 4; j++) {
            pk0[j] = f2bf(o0[4 * rq + j] * rinv);
            pk1[j] = f2bf(o1[4 * rq + j] * rinv);
        }
        *(u16x4*)((char*)Ot + l31 * 128 + ((16 * rq + 8 * hA) ^ X))      = pk0;
        *(u16x4*)((char*)Ot + l31 * 128 + ((64 + 16 * rq + 8 * hA) ^ X)) = pk1;
    }
    __syncthreads();
    #pragma unroll
    for (int p = 0; p < 4; p++) {
        int row = p * 8 + (lane >> 3);
        int cc  = lane & 7;
        short8 vv = *(const short8*)((const char*)Ot + row * 128
                      + ((cc * 16) ^ ((row & 7) << 4)));
        *(short8*)(y + (rowbase + q0 + wave * 32 + row) * E + h * 64 + cc * 8) = vv;
    }
}

// ---------------- launch ----------------
extern "C" void kernel_launch(void* const* d_in, const int* in_sizes, int n_in,
                              void* d_out, int out_size, void* d_ws, size_t ws_size,
                              hipStream_t stream) {
    const float* x     = (const float*)d_in[0];   // [8,1024,1024]
    const float* Wattn = (const float*)d_in[1];   // [1024,3072]
    const float* Wproj = (const float*)d_in[2];   // [1024,1024]
    float* out = (float*)d_out;                   // [8,1024,1024] fp32

    char* ws = (char*)d_ws;
    u16* buf0 = (u16*)ws;                                  // x_bf16, later y_bf16 (16.78 MB)
    u16* wT   = (u16*)(ws + 16777216);                     // W^T bf16 (6.29 MB, reused)
    u16* qkv  = (u16*)(ws + 16777216 + 6291456);           // [8192][3072] bf16 (50.3 MB)

    // x -> bf16
    k_conv_x<<<2048, 256, 0, stream>>>(x, buf0, 8388608 / 4);
    // W_attn^T -> bf16 [3072][1024]
    k_transpose_bf<<<dim3(3072 / 32, 1024 / 32), dim3(32, 8), 0, stream>>>(Wattn, wT, 1024, 3072);
    // qkv = x @ W_attn   (bf16 out): 256x256 8-phase, grid 12x32 = 384 wgs
    k_gemm8<256, 256, true><<<dim3(3072 / 256, 8192 / 256), 512, 0, stream>>>(buf0, wT, qkv, 3072, 1024);
    // W_proj^T -> bf16 [1024][1024]
    k_transpose_bf<<<dim3(1024 / 32, 1024 / 32), dim3(32, 8), 0, stream>>>(Wproj, wT, 1024, 1024);
    // flash attention -> y (reuses buf0)
    k_attn<<<dim3(1024), 256, 0, stream>>>(qkv, buf0);
    // out = y @ W_proj  (fp32 out): 128x256 8-phase, grid 4x64 = 256 wgs
    k_gemm8<128, 256, false><<<dim3(1024 / 256, 8192 / 128), 512, 0, stream>>>(buf0, wT, out, 1024, 1024);
}

// Round 8
// 133.665 us; speedup vs baseline: 1.1329x; 1.0927x over previous
//
#include <hip/hip_runtime.h>
#include <hip/hip_bf16.h>

typedef unsigned short u16;
typedef __attribute__((ext_vector_type(8))) short short8;
typedef __attribute__((ext_vector_type(4))) float f32x4;
typedef __attribute__((ext_vector_type(16))) float f32x16;
typedef __attribute__((ext_vector_type(4))) unsigned short u16x4;

#define DEVINL __device__ __forceinline__

DEVINL u16 f2bf(float f) {
    union { float f; unsigned u; } x; x.f = f;
    unsigned u = x.u;
    u += 0x7fffu + ((u >> 16) & 1u);   // round-to-nearest-even
    return (u16)(u >> 16);
}

DEVINL void gload_lds16(const void* g, void* l) {
    __builtin_amdgcn_global_load_lds(
        (const __attribute__((address_space(1))) unsigned*)g,
        (__attribute__((address_space(3))) unsigned*)l, 16, 0, 0);
}

// XOR swizzle for 128B-stride LDS rows: spreads 16B slots across banks.
DEVINL int swz(int row) { return (((row & 7) ^ ((row >> 3) & 7)) << 4); }

// v_permlane32_swap: after call, for lane<32: a=own a, b=partner's a;
// for lane>=32: a=partner's b, b=own b.
DEVINL void swap32(unsigned& a, unsigned& b) {
#if __has_builtin(__builtin_amdgcn_permlane32_swap)
    typedef __attribute__((ext_vector_type(2))) unsigned uv2;
    uv2 r = __builtin_amdgcn_permlane32_swap(a, b, false, false);
    a = r.x; b = r.y;
#else
    int h = ((int)(threadIdx.x & 63)) >> 5;
    unsigned pa = (unsigned)__shfl_xor((int)a, 32);
    unsigned pb = (unsigned)__shfl_xor((int)b, 32);
    unsigned na = h ? pb : a;
    unsigned nb = h ? b : pa;
    a = na; b = nb;
#endif
}

// ---------------- convert x (fp32 -> bf16), vectorized ----------------
__global__ void k_conv_x(const float* __restrict__ in, u16* __restrict__ out, int n4) {
    int i = blockIdx.x * blockDim.x + threadIdx.x;
    int stride = gridDim.x * blockDim.x;
    for (; i < n4; i += stride) {
        float4 v = ((const float4*)in)[i];
        u16x4 o;
        o.x = f2bf(v.x); o.y = f2bf(v.y); o.z = f2bf(v.z); o.w = f2bf(v.w);
        ((u16x4*)out)[i] = o;
    }
}

// ---------------- transpose + convert: in [R][C] fp32 -> out [C][R] bf16 ----------------
__global__ void k_transpose_bf(const float* __restrict__ in, u16* __restrict__ out, int R, int C) {
    __shared__ float t[32][33];
    int c0 = blockIdx.x * 32, r0 = blockIdx.y * 32;
    int tx = threadIdx.x, ty = threadIdx.y;
    #pragma unroll
    for (int j = 0; j < 32; j += 8)
        t[ty + j][tx] = in[(size_t)(r0 + ty + j) * C + c0 + tx];
    __syncthreads();
    #pragma unroll
    for (int j = 0; j < 32; j += 8)
        out[(size_t)(c0 + ty + j) * R + r0 + tx] = f2bf(t[tx][ty + j]);
}

// ---------------- GEMM: 128x128, BK=64, 2-phase T3-minimum pipeline ----------------
// C[M][N] = A[M][K] @ BT[N][K]^T, bf16 in, bf16/f32 out.
// 4 waves (2x2), per-wave 64x64. Double-buffered LDS (2 x 32KB = 64KB -> 2 blocks/CU).
// Per K-step of 64: stage(t+1) FIRST (overlaps compute), ds_reads + 32 MFMA
// (compiler-scheduled lgkm interleave), then ONE vmcnt(0) + ONE barrier.
template<bool OUT_BF16>
__global__ __launch_bounds__(256, 2)
void k_gemm2(const u16* __restrict__ A, const u16* __restrict__ BT,
             void* __restrict__ C, int N, int K) {
    __shared__ char lds[2 * 32768];    // per buf: A @0 (16KB), B @16384 (16KB)

    const int tid  = threadIdx.x;
    const int lane = tid & 63;
    const int lo   = lane & 15;
    const int hi   = lane >> 4;
    const int wave = tid >> 6;
    const int wm   = wave >> 1;
    const int wn   = wave & 1;

    // XCD-aware bijective block swizzle (nwg % 8 == 0 for our grids)
    const int gx   = gridDim.x;
    const int nwg  = gx * gridDim.y;
    const int orig = blockIdx.y * gx + blockIdx.x;
    const int wg   = (orig & 7) * (nwg >> 3) + (orig >> 3);
    const long row0 = (long)(wg / gx) * 128;
    const long col0 = (long)(wg % gx) * 128;

    const int NT = K >> 6;             // BK = 64

    const int srow = tid >> 3;                         // 0..31 (row within 32-row chunk)
    const int gsb  = ((tid & 7) ^ (srow & 7)) << 4;    // pre-swizzled source byte

    auto stage = [&](int t) {
        char* base = lds + (t & 1) * 32768;
        #pragma unroll
        for (int c = 0; c < 4; c++)
            gload_lds16((const char*)(A + (row0 + c * 32 + srow) * (size_t)K + t * 64) + gsb,
                        base + c * 4096 + tid * 16);
        #pragma unroll
        for (int c = 0; c < 4; c++)
            gload_lds16((const char*)(BT + (col0 + c * 32 + srow) * (size_t)K + t * 64) + gsb,
                        base + 16384 + c * 4096 + tid * 16);
    };

    f32x4 acc[4][4] = {};

    stage(0);
    asm volatile("s_waitcnt vmcnt(0)" ::: "memory");
    __builtin_amdgcn_s_barrier();

    for (int t = 0; t < NT; t++) {
        if (t + 1 < NT) stage(t + 1);               // issue early: hides under MFMA
        const char* ab = lds + (t & 1) * 32768;
        const char* bb = ab + 16384;
        #pragma unroll
        for (int kk = 0; kk < 2; kk++) {
            short8 af[4], bf[4];
            #pragma unroll
            for (int m = 0; m < 4; m++) {
                int r = wm * 64 + m * 16 + lo;
                af[m] = *(const short8*)(ab + r * 128 + ((kk * 64 + hi * 16) ^ ((r & 7) << 4)));
            }
            #pragma unroll
            for (int n = 0; n < 4; n++) {
                int r = wn * 64 + n * 16 + lo;
                bf[n] = *(const short8*)(bb + r * 128 + ((kk * 64 + hi * 16) ^ ((r & 7) << 4)));
            }
            #pragma unroll
            for (int m = 0; m < 4; m++)
                #pragma unroll
                for (int n = 0; n < 4; n++)
                    acc[m][n] = __builtin_amdgcn_mfma_f32_16x16x32_bf16(af[m], bf[n], acc[m][n], 0, 0, 0);
        }
        if (t + 1 < NT) {
            asm volatile("s_waitcnt vmcnt(0)" ::: "memory");   // t+1 resident
            __builtin_amdgcn_s_barrier();                      // all reads of buf[t] done
        }
    }

    // ---- epilogue ----
    #pragma unroll
    for (int m = 0; m < 4; m++)
        #pragma unroll
        for (int n = 0; n < 4; n++)
            #pragma unroll
            for (int r = 0; r < 4; r++) {
                long row = row0 + wm * 64 + m * 16 + hi * 4 + r;
                long col = col0 + wn * 64 + n * 16 + lo;
                if constexpr (OUT_BF16)
                    ((u16*)C)[row * (size_t)N + col] = f2bf(acc[m][n][r]);
                else
                    ((float*)C)[row * (size_t)N + col] = acc[m][n][r];
            }
}

// ---------------- Flash attention v3: swapped-operand 32x32, in-register softmax --------
// grid: 1024 blocks (8 qi x 128 bh), longest-first. Block = 4 waves x 32 q-rows = 128 q.
#define SCALE_L2E 0.18033688011112042f  // (1/sqrt(64)) * log2(e)

__global__ __launch_bounds__(256, 2)
void k_attn(const u16* __restrict__ qkv, u16* __restrict__ y) {
    constexpr int S = 1024, E = 1024, TE = 3072;
    __shared__ u16 Kt[64 * 64];   // [kv][d], swizzled rows (128B)
    __shared__ u16 Vt[64 * 64];   // [d][kv], swizzled rows (128B)

    const int tid  = threadIdx.x;
    const int lane = tid & 63;
    const int l31  = lane & 31;
    const int hA   = lane >> 5;
    const int wave = tid >> 6;

    const int qi = 7 - (int)(blockIdx.x >> 7);   // longest first
    const int bh = blockIdx.x & 127;
    const int b  = bh >> 4;
    const int h  = bh & 15;
    const int q0 = qi * 128;
    const size_t rowbase = (size_t)b * S;
    const int qg = q0 + wave * 32 + l31;         // this lane's q-row

    short8 qf[4];
    {
        const u16* qp = qkv + (rowbase + qg) * TE + h * 64 + hA * 8;
        #pragma unroll
        for (int kd = 0; kd < 4; kd++) qf[kd] = *(const short8*)(qp + kd * 16);
    }

    f32x16 o0 = {}, o1 = {};
    float ms = -1e30f, lsum = 0.f;

    const int kr0 = (wave << 3) + (lane >> 3);
    const int kcb = (lane & 7) * 16;
    const int vkv = (tid >> 3) * 2;
    const int vdc = (tid & 7) * 8;

    const int ntiles = 2 * qi + 2;
    for (int t = 0; t < ntiles; ++t) {
        const int kv0 = t * 64;
        __syncthreads();
        #pragma unroll
        for (int it = 0; it < 2; it++) {
            int r = kr0 + it * 32;
            const char* src = (const char*)qkv
                + (((rowbase + kv0 + r) * TE + E + h * 64) << 1) + (kcb ^ swz(r));
            gload_lds16(src, (char*)Kt + wave * 1024 + it * 4096);
        }
        {
            const u16* vsrc = qkv + (rowbase + kv0 + vkv) * TE + 2 * E + h * 64 + vdc;
            short8 v0 = *(const short8*)vsrc;
            short8 v1 = *(const short8*)(vsrc + TE);
            #pragma unroll
            for (int j = 0; j < 8; j++) {
                int d = vdc + j;
                unsigned val = (unsigned)(u16)v0[j] | ((unsigned)(u16)v1[j] << 16);
                *(unsigned*)((char*)Vt + d * 128 + ((vkv * 2) ^ swz(d))) = val;
            }
        }
        __syncthreads();

        const bool active = (kv0 <= q0 + wave * 32 + 31);
        if (!active) continue;

        f32x16 s0 = {}, s1 = {};
        #pragma unroll
        for (int kd = 0; kd < 4; kd++) {
            int r0 = l31, r1 = 32 + l31;
            short8 ka0 = *(const short8*)((const char*)Kt + r0 * 128 + ((kd * 32 + hA * 16) ^ swz(r0)));
            short8 ka1 = *(const short8*)((const char*)Kt + r1 * 128 + ((kd * 32 + hA * 16) ^ swz(r1)));
            s0 = __builtin_amdgcn_mfma_f32_32x32x16_bf16(ka0, qf[kd], s0, 0, 0, 0);
            s1 = __builtin_amdgcn_mfma_f32_32x32x16_bf16(ka1, qf[kd], s1, 0, 0, 0);
        }

        if (kv0 + 63 > q0 + wave * 32) {
            #pragma unroll
            for (int r = 0; r < 16; r++) {
                int kvr = kv0 + ((r & 3) + 8 * (r >> 2) + 4 * hA);
                if (kvr > qg)      s0[r] = -1e30f;
                if (kvr + 32 > qg) s1[r] = -1e30f;
            }
        }

        float pm = s0[0];
        #pragma unroll
        for (int r = 1; r < 16; r++) pm = fmaxf(pm, s0[r]);
        #pragma unroll
        for (int r = 0; r < 16; r++) pm = fmaxf(pm, s1[r]);
        pm = fmaxf(pm, __shfl_xor(pm, 32));
        float pms = pm * SCALE_L2E;
        if (__any(pms - ms > 8.0f)) {
            float msn = fmaxf(ms, pms);
            float alpha = exp2f(ms - msn);
            ms = msn;
            lsum *= alpha;
            #pragma unroll
            for (int r = 0; r < 16; r++) { o0[r] *= alpha; o1[r] *= alpha; }
        }

        float part = 0.f;
        #pragma unroll
        for (int r = 0; r < 16; r++) {
            float p0 = exp2f(s0[r] * SCALE_L2E - ms);
            float p1 = exp2f(s1[r] * SCALE_L2E - ms);
            s0[r] = p0; s1[r] = p1;
            part += p0 + p1;
        }
        lsum += part + __shfl_xor(part, 32);

        unsigned w0[8], w1[8];
        #pragma unroll
        for (int j = 0; j < 8; j++) {
            asm("v_cvt_pk_bf16_f32 %0, %1, %2" : "=v"(w0[j]) : "v"(s0[2 * j]), "v"(s0[2 * j + 1]));
            asm("v_cvt_pk_bf16_f32 %0, %1, %2" : "=v"(w1[j]) : "v"(s1[2 * j]), "v"(s1[2 * j + 1]));
        }

        #define PV_TILE(W, ST)                                                              \
        {                                                                                   \
            _Pragma("unroll")                                                               \
            for (int kkl = 0; kkl < 2; kkl++) {                                             \
                unsigned a  = W[4 * kkl],     bsw = W[4 * kkl + 2];                         \
                unsigned a2 = W[4 * kkl + 1], b2  = W[4 * kkl + 3];                         \
                swap32(a, bsw); swap32(a2, b2);                                             \
                union { int4 i; short8 s; } u;                                              \
                u.i = make_int4((int)a, (int)a2, (int)bsw, (int)b2);                        \
                {                                                                           \
                    int row = l31;                                                          \
                    short8 va = *(const short8*)((const char*)Vt + row * 128                \
                                  + (((ST) * 64 + kkl * 32 + hA * 16) ^ swz(row)));         \
                    o0 = __builtin_amdgcn_mfma_f32_32x32x16_bf16(va, u.s, o0, 0, 0, 0);     \
                }                                                                           \
                {                                                                           \
                    int row = 32 + l31;                                                     \
                    short8 va = *(const short8*)((const char*)Vt + row * 128                \
                                  + (((ST) * 64 + kkl * 32 + hA * 16) ^ swz(row)));         \
                    o1 = __builtin_amdgcn_mfma_f32_32x32x16_bf16(va, u.s, o1, 0, 0, 0);     \
                }                                                                           \
            }                                                                               \
        }
        PV_TILE(w0, 0)
        PV_TILE(w1, 1)
        #undef PV_TILE
    }

    __syncthreads();
    float rinv = 1.0f / lsum;
    u16* Ot = (wave < 2 ? Kt : Vt) + (wave & 1) * 2048;
    const int X = (l31 & 7) << 4;
    #pragma unroll
    for (int rq = 0; rq < 4; rq++) {
        u16x4 pk0, pk1;
        #pragma unroll
        for (int j = 0; j < 4; j++) {
            pk0[j] = f2bf(o0[4 * rq + j] * rinv);
            pk1[j] = f2bf(o1[4 * rq + j] * rinv);
        }
        *(u16x4*)((char*)Ot + l31 * 128 + ((16 * rq + 8 * hA) ^ X))      = pk0;
        *(u16x4*)((char*)Ot + l31 * 128 + ((64 + 16 * rq + 8 * hA) ^ X)) = pk1;
    }
    __syncthreads();
    #pragma unroll
    for (int p = 0; p < 4; p++) {
        int row = p * 8 + (lane >> 3);
        int cc  = lane & 7;
        short8 vv = *(const short8*)((const char*)Ot + row * 128
                      + ((cc * 16) ^ ((row & 7) << 4)));
        *(short8*)(y + (rowbase + q0 + wave * 32 + row) * E + h * 64 + cc * 8) = vv;
    }
}

// ---------------- launch ----------------
extern "C" void kernel_launch(void* const* d_in, const int* in_sizes, int n_in,
                              void* d_out, int out_size, void* d_ws, size_t ws_size,
                              hipStream_t stream) {
    const float* x     = (const float*)d_in[0];   // [8,1024,1024]
    const float* Wattn = (const float*)d_in[1];   // [1024,3072]
    const float* Wproj = (const float*)d_in[2];   // [1024,1024]
    float* out = (float*)d_out;                   // [8,1024,1024] fp32

    char* ws = (char*)d_ws;
    u16* buf0 = (u16*)ws;                                  // x_bf16, later y_bf16 (16.78 MB)
    u16* wT   = (u16*)(ws + 16777216);                     // W^T bf16 (6.29 MB, reused)
    u16* qkv  = (u16*)(ws + 16777216 + 6291456);           // [8192][3072] bf16 (50.3 MB)

    // x -> bf16
    k_conv_x<<<2048, 256, 0, stream>>>(x, buf0, 8388608 / 4);
    // W_attn^T -> bf16 [3072][1024]
    k_transpose_bf<<<dim3(3072 / 32, 1024 / 32), dim3(32, 8), 0, stream>>>(Wattn, wT, 1024, 3072);
    // qkv = x @ W_attn   (bf16 out): 128x128 2-phase, grid 24x64 = 1536 wgs
    k_gemm2<true><<<dim3(3072 / 128, 8192 / 128), 256, 0, stream>>>(buf0, wT, qkv, 3072, 1024);
    // W_proj^T -> bf16 [1024][1024]
    k_transpose_bf<<<dim3(1024 / 32, 1024 / 32), dim3(32, 8), 0, stream>>>(Wproj, wT, 1024, 1024);
    // flash attention -> y (reuses buf0)
    k_attn<<<dim3(1024), 256, 0, stream>>>(qkv, buf0);
    // out = y @ W_proj  (fp32 out): 128x128 2-phase, grid 8x64 = 512 wgs
    k_gemm2<false><<<dim3(1024 / 128, 8192 / 128), 256, 0, stream>>>(buf0, wT, out, 1024, 1024);
}